// Round 6
// baseline (232.831 us; speedup 1.0000x reference)
//
#include <hip/hip_runtime.h>
#include <hip/hip_bf16.h>

#define DEG        16
#define IN_FEATS   256
#define NUM_HEADS  4
#define OUT_FEATS  64
#define HF         256
#define NEG_SLOPE  0.2f

#define CPITCH 264     // 256 + 8 (epilogue store-transpose pitch)

typedef __attribute__((ext_vector_type(8))) short  short8;
typedef __attribute__((ext_vector_type(4))) float  floatx4;
typedef unsigned short ushortT;

__device__ __forceinline__ unsigned short f2bf(float f) {
    union { float f; unsigned u; } v; v.f = f;
    unsigned r = v.u + 0x7fffu + ((v.u >> 16) & 1u);   // round-to-nearest-even
    return (unsigned short)(r >> 16);
}
__device__ __forceinline__ float bf2f(unsigned short u) {
    union { unsigned u; float f; } v; v.u = ((unsigned)u) << 16;
    return v.f;
}
__device__ __forceinline__ unsigned pk2(float lo, float hi) {
    return (unsigned)f2bf(lo) | ((unsigned)f2bf(hi) << 16);
}

// async 16B global -> LDS (wave-uniform LDS base + lane*16)
__device__ __forceinline__ void load16_g2l(const void* g, void* lds) {
    __builtin_amdgcn_global_load_lds(
        (const __attribute__((address_space(1))) unsigned int*)(unsigned long long)g,
        (__attribute__((address_space(3))) unsigned int*)(unsigned int)(unsigned long long)lds,
        16, 0, 0);
}

// ---------------------------------------------------------------------------
// Kernel 0: prep.  Blocks [0,nfb): featb = bf16(feat) (8 elems/thread).
//           Blocks [nfb,nfb+256): Wt[n][k] = bf16(W[k][n]).
// ---------------------------------------------------------------------------
__global__ __launch_bounds__(256) void prep(
    const float* __restrict__ feat, const float* __restrict__ W,
    ushortT* __restrict__ featb, ushortT* __restrict__ Wt,
    int nfb, long long totalElems)
{
    int b = blockIdx.x;
    if (b < nfb) {
        long long base = (long long)b * 2048 + (long long)threadIdx.x * 8;
        if (base + 8 <= totalElems) {
            float4 v0 = *(const float4*)&feat[base];
            float4 v1 = *(const float4*)&feat[base + 4];
            uint4 o;
            o.x = pk2(v0.x, v0.y); o.y = pk2(v0.z, v0.w);
            o.z = pk2(v1.x, v1.y); o.w = pk2(v1.z, v1.w);
            *(uint4*)&featb[base] = o;
        }
    } else {
        int n = b - nfb;
        int k = threadIdx.x;
        Wt[n * 256 + k] = f2bf(W[k * 256 + n]);
    }
}

// ---------------------------------------------------------------------------
// Kernel 1: h = featb @ W via MFMA bf16 (round-4 core).  Epilogue now stores
// h in XCD-SLICED layout: Hs[s][n][32], s = head*2 + half  (slice = 3.2 MB,
// fits one XCD's 4 MB L2).  Scores epilogue unchanged.
// ---------------------------------------------------------------------------
__global__ __launch_bounds__(256, 3) void gat_gemm_mfma2(
    const ushortT* __restrict__ featb,        // bf16 [M,256]
    const ushortT* __restrict__ Bt,           // Wt bf16 [n=256][k=256]
    const float* __restrict__ attn_l,         // [256]
    const float* __restrict__ attn_r,         // [256]
    ushortT* __restrict__ Hs,                 // h bf16 sliced [8][M][32]
    float* __restrict__ arow,                 // [M,4]
    float* __restrict__ acol,                 // [M,4]
    int M)
{
    __shared__ __align__(16) ushortT SMEM[64 * CPITCH];
    ushortT* As = SMEM;
    ushortT* Cs = SMEM;

    const int tid  = threadIdx.x;
    const int wave = tid >> 6;       // == head
    const int lane = tid & 63;
    const int l15  = lane & 15;
    const int quad = lane >> 4;
    const int rowBase = blockIdx.x * 64;

    #pragma unroll
    for (int t = 0; t < 8; ++t) {
        int row  = wave * 16 + t * 2 + (lane >> 5);
        int cst  = lane & 31;
        int cg   = cst ^ (row & 7);
        int grow = rowBase + row; if (grow > M - 1) grow = M - 1;
        const ushortT* g = featb + (long long)grow * 256 + cg * 8;
        load16_g2l(g, &As[(wave * 512 + t * 64) * 8]);
    }

    short8 bbuf[2][4];
    #pragma unroll
    for (int ni = 0; ni < 4; ++ni)
        bbuf[0][ni] = *(const short8*)&Bt[(wave * 64 + ni * 16 + l15) * 256 + quad * 8];

    __syncthreads();

    floatx4 acc[4][4] = {};

    #pragma unroll
    for (int ks = 0; ks < 8; ++ks) {
        if (ks < 7) {
            #pragma unroll
            for (int ni = 0; ni < 4; ++ni)
                bbuf[(ks + 1) & 1][ni] = *(const short8*)
                    &Bt[(wave * 64 + ni * 16 + l15) * 256 + (ks + 1) * 32 + quad * 8];
        }
        short8 af[4];
        #pragma unroll
        for (int mi = 0; mi < 4; ++mi) {
            int row = mi * 16 + l15;
            int q   = ks * 4 + quad;
            int cst = q ^ (row & 7);
            af[mi] = *(const short8*)&As[row * 256 + cst * 8];
        }
        #pragma unroll
        for (int mi = 0; mi < 4; ++mi)
            #pragma unroll
            for (int ni = 0; ni < 4; ++ni)
                acc[mi][ni] = __builtin_amdgcn_mfma_f32_16x16x32_bf16(
                    af[mi], bbuf[ks & 1][ni], acc[mi][ni], 0, 0, 0);
    }

    // ---- Epilogue A: attention scores (wave == head).
    float al[4], ar[4];
    #pragma unroll
    for (int ni = 0; ni < 4; ++ni) {
        al[ni] = attn_l[wave * 64 + ni * 16 + l15];
        ar[ni] = attn_r[wave * 64 + ni * 16 + l15];
    }
    #pragma unroll
    for (int mi = 0; mi < 4; ++mi) {
        #pragma unroll
        for (int reg = 0; reg < 4; ++reg) {
            float pl = 0.f, pr = 0.f;
            #pragma unroll
            for (int ni = 0; ni < 4; ++ni) {
                pl = fmaf(acc[mi][ni][reg], al[ni], pl);
                pr = fmaf(acc[mi][ni][reg], ar[ni], pr);
            }
            #pragma unroll
            for (int off = 8; off >= 1; off >>= 1) {
                pl += __shfl_xor(pl, off, 64);
                pr += __shfl_xor(pr, off, 64);
            }
            if (l15 == 0) {
                int gr = rowBase + mi * 16 + quad * 4 + reg;
                if (gr < M) {
                    arow[gr * NUM_HEADS + wave] = pl;
                    acol[gr * NUM_HEADS + wave] = pr;
                }
            }
        }
    }

    __syncthreads();

    // ---- Epilogue B: h -> bf16 into Cs (row-major 256-wide, pitch 264).
    #pragma unroll
    for (int mi = 0; mi < 4; ++mi)
        #pragma unroll
        for (int ni = 0; ni < 4; ++ni)
            #pragma unroll
            for (int reg = 0; reg < 4; ++reg)
                Cs[(mi * 16 + quad * 4 + reg) * CPITCH + wave * 64 + ni * 16 + l15] =
                    f2bf(acc[mi][ni][reg]);
    __syncthreads();

    // ---- Sliced store: slice s holds cols [s*32, s*32+32).  Per slice,
    // thread tid writes row tid>>2, chunk (tid&3)*8 -> contiguous 1KB/wave.
    const size_t strideS = (size_t)M * 32;
    const int r  = tid >> 2;
    const int c  = (tid & 3) << 3;
    const int gr = rowBase + r;
    if (gr < M) {
        #pragma unroll
        for (int s = 0; s < 8; ++s) {
            uint4 v = *(const uint4*)&Cs[r * CPITCH + s * 32 + c];
            *(uint4*)&Hs[(size_t)s * strideS + (size_t)gr * 32 + c] = v;
        }
    }
}

// ---------------------------------------------------------------------------
// Kernel 2 (v4): XCD-sliced aggregate.  slice = blockIdx & 7 (round-robin
// blockIdx->XCD keeps each XCD on ONE 3.2 MB slice -> L2-resident).
// Wave = one node: lanes replicate 16 edge scores 4x (width-16 softmax),
// then 4 iters x 4 edges: 16 lanes x 4B = one 64B line per edge row-slice.
// Cross-group reduce via shfl; lanes 0-15 store float2 (128 B/node/slice).
// ---------------------------------------------------------------------------
__global__ __launch_bounds__(256) void gat_aggregate4(
    const ushortT* __restrict__ Hs,          // bf16 [8][N][32]
    const float* __restrict__ arow,          // [N,4]
    const float* __restrict__ acol,          // [N,4]
    const int* __restrict__ col_ind,         // [N*16]
    float* __restrict__ out,                 // [N,256] fp32
    int N)
{
    const int s    = blockIdx.x & 7;
    const int head = s >> 1;
    const int half = s & 1;
    const int wave = threadIdx.x >> 6;
    const int lane = threadIdx.x & 63;
    const int l15  = lane & 15;
    const int n    = (blockIdx.x >> 3) * 4 + wave;
    if (n >= N) return;

    const ushortT* Hslice = Hs + (size_t)s * N * 32;

    // ---- scores for this head (computed redundantly per half; cheap).
    int   src_e = col_ind[n * DEG + l15];
    float e = arow[n * NUM_HEADS + head] + acol[src_e * NUM_HEADS + head];
    e = (e > 0.f) ? e : NEG_SLOPE * e;

    float m = e;
    #pragma unroll
    for (int off = 8; off >= 1; off >>= 1)
        m = fmaxf(m, __shfl_xor(m, off, 16));
    float ex = __expf(e - m);
    float su = ex;
    #pragma unroll
    for (int off = 8; off >= 1; off >>= 1)
        su += __shfl_xor(su, off, 16);
    float alpha = ex / su;           // lane l15 holds alpha[edge=l15] (4 replicas)

    // ---- gather: 4 iterations x 4 edges; lane group g=lane>>4 -> edge it*4+g.
    float acc0 = 0.f, acc1 = 0.f;
    #pragma unroll
    for (int it = 0; it < 4; ++it) {
        int   j  = it * 4 + (lane >> 4);
        int   sj = __shfl(src_e, j, 64);
        float a  = __shfl(alpha, j, 64);
        unsigned v = *(const unsigned*)&Hslice[(size_t)sj * 32 + l15 * 2];
        acc0 = fmaf(a, bf2f((unsigned short)(v & 0xffffu)), acc0);
        acc1 = fmaf(a, bf2f((unsigned short)(v >> 16)),     acc1);
    }
    acc0 += __shfl_xor(acc0, 16, 64); acc0 += __shfl_xor(acc0, 32, 64);
    acc1 += __shfl_xor(acc1, 16, 64); acc1 += __shfl_xor(acc1, 32, 64);

    if (lane < 16) {
        *(float2*)&out[(size_t)n * HF + head * 64 + half * 32 + l15 * 2] =
            make_float2(acc0, acc1);
    }
}

// ---------------------------------------------------------------------------
extern "C" void kernel_launch(void* const* d_in, const int* in_sizes, int n_in,
                              void* d_out, int out_size, void* d_ws, size_t ws_size,
                              hipStream_t stream) {
    // Inputs: row_ptr, col_ind, col_ptr, row_ind, feat, W, attn_l, attn_r
    const int*   col_ind = (const int*)  d_in[1];
    const float* feat    = (const float*)d_in[4];
    const float* W       = (const float*)d_in[5];
    const float* attn_l  = (const float*)d_in[6];
    const float* attn_r  = (const float*)d_in[7];
    float* out = (float*)d_out;

    const int N = in_sizes[0] - 1;   // 50000

    // featb scratch lives in d_out (25.6 MB < 51.2 MB; aggregate rewrites all
    // of d_out afterwards).  ws: Hs bf16 [8][N][32] | arow | acol | Wt.
    ushortT* featb = (ushortT*)d_out;
    ushortT* Hs    = (ushortT*)d_ws;
    float*   arow  = (float*)(Hs + (size_t)N * HF);
    float*   acol  = arow + (size_t)N * NUM_HEADS;
    ushortT* Wt    = (ushortT*)(acol + (size_t)N * NUM_HEADS);

    const long long totalElems = (long long)N * HF;
    const int nfb = (int)((totalElems + 2047) / 2048);

    prep<<<nfb + 256, 256, 0, stream>>>(feat, W, featb, Wt, nfb, totalElems);

    dim3 ggrid((N + 63) / 64);
    gat_gemm_mfma2<<<ggrid, 256, 0, stream>>>(featb, Wt, attn_l, attn_r,
                                              Hs, arow, acol, N);

    dim3 agrid(((N + 3) / 4) * 8);
    gat_aggregate4<<<agrid, 256, 0, stream>>>(Hs, arow, acol, col_ind, out, N);
}

// Round 8
// 193.725 us; speedup vs baseline: 1.2019x; 1.2019x over previous
//
#include <hip/hip_runtime.h>
#include <hip/hip_bf16.h>

#define DEG        16
#define IN_FEATS   256
#define NUM_HEADS  4
#define OUT_FEATS  64
#define HF         256
#define NEG_SLOPE  0.2f

#define CPITCH 264     // 256 + 8 (epilogue store-transpose pitch)

typedef __attribute__((ext_vector_type(8))) short  short8;
typedef __attribute__((ext_vector_type(4))) float  floatx4;
typedef unsigned short ushortT;

__device__ __forceinline__ unsigned short f2bf(float f) {
    union { float f; unsigned u; } v; v.f = f;
    unsigned r = v.u + 0x7fffu + ((v.u >> 16) & 1u);   // round-to-nearest-even
    return (unsigned short)(r >> 16);
}
__device__ __forceinline__ float bf2f(unsigned short u) {
    union { unsigned u; float f; } v; v.u = ((unsigned)u) << 16;
    return v.f;
}
// packed fp32x2 -> bf16x2 (manual RTNE pack; verified absmax since round 2)
__device__ __forceinline__ unsigned cvt2(float lo, float hi) {
    return (unsigned)f2bf(lo) | ((unsigned)f2bf(hi) << 16);
}

// ---------------------------------------------------------------------------
// Kernel 0: Wt[n][k] = bf16(W[k][n])  (256x256, tiny)
// ---------------------------------------------------------------------------
__global__ __launch_bounds__(256) void conv_wt(
    const float* __restrict__ W, ushortT* __restrict__ Wt)
{
    int n = blockIdx.x;
    int k = threadIdx.x;
    Wt[n * 256 + k] = f2bf(W[k * 256 + n]);
}

// ---------------------------------------------------------------------------
// Kernel 1: h = feat @ W via MFMA bf16, fp32->bf16 conversion FUSED into the
// A-staging (packed cvt + swizzled ds_write; replaces the separate prep
// pass).  Tile 64x256, full K=256, single staging barrier.
// B: direct global->VGPR per wave (L2-resident Wt), 1-step prefetch.
// Epilogue: fused attention scores + row-major bf16 Hb store via LDS
// transpose (byte-identical to the round-4/5 verified kernel).
// ---------------------------------------------------------------------------
__global__ __launch_bounds__(256, 3) void gat_gemm_fused(
    const float* __restrict__ feat,           // fp32 [M,256]
    const ushortT* __restrict__ Bt,           // Wt bf16 [n=256][k=256]
    const float* __restrict__ attn_l,         // [256]
    const float* __restrict__ attn_r,         // [256]
    ushortT* __restrict__ Hb,                 // h bf16 [M,256]
    float* __restrict__ arow,                 // [M,4]
    float* __restrict__ acol,                 // [M,4]
    int M)
{
    // As: 64 rows x 32 chunks x 16B = 32 KB (XOR-swizzled). Cs overlays.
    __shared__ __align__(16) ushortT SMEM[64 * CPITCH];
    ushortT* As = SMEM;
    ushortT* Cs = SMEM;

    const int tid  = threadIdx.x;
    const int wave = tid >> 6;       // == head
    const int lane = tid & 63;
    const int l15  = lane & 15;
    const int quad = lane >> 4;
    const int rowBase = blockIdx.x * 64;

    // ---- Prefetch B for ks=0 (independent of LDS staging).
    short8 bbuf[2][4];
    #pragma unroll
    for (int ni = 0; ni < 4; ++ni)
        bbuf[0][ni] = *(const short8*)&Bt[(wave * 64 + ni * 16 + l15) * 256 + quad * 8];

    // ---- Stage A: 64 rows x 256 cols fp32 -> bf16 swizzled LDS.
    // 4096 float4s total; 2 passes x 8 per thread (8 loads in flight/pass).
    // Layout: 16B chunk cg of row r stored at chunk (cg ^ (r&7))  [verified r4].
    #pragma unroll
    for (int pass = 0; pass < 2; ++pass) {
        float4 v[8];
        #pragma unroll
        for (int i = 0; i < 8; ++i) {
            int id  = pass * 2048 + i * 256 + tid;   // flat float4 index
            int row = id >> 6;                        // 64 float4 per row
            int c4  = id & 63;
            int gr  = rowBase + row; if (gr > M - 1) gr = M - 1;
            v[i] = *(const float4*)&feat[(size_t)gr * 256 + c4 * 4];
        }
        #pragma unroll
        for (int i = 0; i < 8; ++i) {
            int id   = pass * 2048 + i * 256 + tid;
            int row  = id >> 6;
            int c4   = id & 63;
            int cg   = c4 >> 1;                       // 16B chunk col (0..31)
            int half = c4 & 1;
            uint2 w = make_uint2(cvt2(v[i].x, v[i].y), cvt2(v[i].z, v[i].w));
            *(uint2*)&As[row * 256 + ((cg ^ (row & 7)) << 3) + half * 4] = w;
        }
    }

    __syncthreads();

    floatx4 acc[4][4] = {};

    #pragma unroll
    for (int ks = 0; ks < 8; ++ks) {
        if (ks < 7) {
            #pragma unroll
            for (int ni = 0; ni < 4; ++ni)
                bbuf[(ks + 1) & 1][ni] = *(const short8*)
                    &Bt[(wave * 64 + ni * 16 + l15) * 256 + (ks + 1) * 32 + quad * 8];
        }
        short8 af[4];
        #pragma unroll
        for (int mi = 0; mi < 4; ++mi) {
            int row = mi * 16 + l15;
            int q   = ks * 4 + quad;
            int cst = q ^ (row & 7);
            af[mi] = *(const short8*)&As[row * 256 + cst * 8];
        }
        #pragma unroll
        for (int mi = 0; mi < 4; ++mi)
            #pragma unroll
            for (int ni = 0; ni < 4; ++ni)
                acc[mi][ni] = __builtin_amdgcn_mfma_f32_16x16x32_bf16(
                    af[mi], bbuf[ks & 1][ni], acc[mi][ni], 0, 0, 0);
    }

    // ---- Epilogue A: attention scores (wave == head).
    float al[4], ar[4];
    #pragma unroll
    for (int ni = 0; ni < 4; ++ni) {
        al[ni] = attn_l[wave * 64 + ni * 16 + l15];
        ar[ni] = attn_r[wave * 64 + ni * 16 + l15];
    }
    #pragma unroll
    for (int mi = 0; mi < 4; ++mi) {
        #pragma unroll
        for (int reg = 0; reg < 4; ++reg) {
            float pl = 0.f, pr = 0.f;
            #pragma unroll
            for (int ni = 0; ni < 4; ++ni) {
                pl = fmaf(acc[mi][ni][reg], al[ni], pl);
                pr = fmaf(acc[mi][ni][reg], ar[ni], pr);
            }
            #pragma unroll
            for (int off = 8; off >= 1; off >>= 1) {
                pl += __shfl_xor(pl, off, 64);   // stays within 16-lane quad
                pr += __shfl_xor(pr, off, 64);
            }
            if (l15 == 0) {
                int gr = rowBase + mi * 16 + quad * 4 + reg;
                if (gr < M) {
                    arow[gr * NUM_HEADS + wave] = pl;
                    acol[gr * NUM_HEADS + wave] = pr;
                }
            }
        }
    }

    __syncthreads();   // all As reads complete before Cs overlay

    // ---- Epilogue B: h -> bf16, coalesced row-major store via LDS transpose.
    #pragma unroll
    for (int mi = 0; mi < 4; ++mi)
        #pragma unroll
        for (int ni = 0; ni < 4; ++ni)
            #pragma unroll
            for (int reg = 0; reg < 4; ++reg)
                Cs[(mi * 16 + quad * 4 + reg) * CPITCH + wave * 64 + ni * 16 + l15] =
                    f2bf(acc[mi][ni][reg]);
    __syncthreads();

    #pragma unroll
    for (int i = 0; i < 8; ++i) {
        int f  = tid + 256 * i;
        int r  = f >> 5;
        int c8 = (f & 31) << 3;
        int gr = rowBase + r;
        if (gr < M) {
            uint4 v = *(const uint4*)&Cs[r * CPITCH + c8];
            *(uint4*)&Hb[(size_t)gr * HF + c8] = v;
        }
    }
}

// ---------------------------------------------------------------------------
// Kernel 2 (v3, round-5 verified): ONE WAVE PER NODE. No LDS, no barriers.
// ---------------------------------------------------------------------------
__global__ __launch_bounds__(256) void gat_aggregate3(
    const ushortT* __restrict__ Hb,          // bf16 [N,256]
    const float* __restrict__ arow,          // [N,4]
    const float* __restrict__ acol,          // [N,4]
    const int* __restrict__ col_ind,         // [N*16]
    float* __restrict__ out,                 // [N,256] fp32
    int N)
{
    const int tid  = threadIdx.x;
    const int wave = tid >> 6;
    const int lane = tid & 63;
    const int n    = blockIdx.x * 4 + wave;
    if (n >= N) return;

    const int j16  = lane & 15;
    const int hd16 = lane >> 4;

    int   src_e = col_ind[n * DEG + j16];
    float e = arow[n * NUM_HEADS + hd16] + acol[src_e * NUM_HEADS + hd16];
    e = (e > 0.f) ? e : NEG_SLOPE * e;

    float m = e;
    #pragma unroll
    for (int off = 8; off >= 1; off >>= 1)
        m = fmaxf(m, __shfl_xor(m, off, 16));
    float ex = __expf(e - m);
    float s = ex;
    #pragma unroll
    for (int off = 8; off >= 1; off >>= 1)
        s += __shfl_xor(s, off, 16);
    float alpha = ex / s;                  // alpha[head=hd16][edge=j16]

    const int myHeadBase = (lane >> 4) << 4;
    float acc0 = 0.f, acc1 = 0.f, acc2 = 0.f, acc3 = 0.f;

    #pragma unroll
    for (int j = 0; j < DEG; ++j) {
        int   sj = __shfl(src_e, j, 64);
        float a  = __shfl(alpha, myHeadBase + j, 64);
        uint2 v = *(const uint2*)&Hb[(size_t)sj * HF + lane * 4];
        acc0 = fmaf(a, bf2f((unsigned short)(v.x & 0xffffu)), acc0);
        acc1 = fmaf(a, bf2f((unsigned short)(v.x >> 16)),     acc1);
        acc2 = fmaf(a, bf2f((unsigned short)(v.y & 0xffffu)), acc2);
        acc3 = fmaf(a, bf2f((unsigned short)(v.y >> 16)),     acc3);
    }

    *(float4*)&out[(size_t)n * HF + lane * 4] = make_float4(acc0, acc1, acc2, acc3);
}

// ---------------------------------------------------------------------------
extern "C" void kernel_launch(void* const* d_in, const int* in_sizes, int n_in,
                              void* d_out, int out_size, void* d_ws, size_t ws_size,
                              hipStream_t stream) {
    // Inputs: row_ptr, col_ind, col_ptr, row_ind, feat, W, attn_l, attn_r
    const int*   col_ind = (const int*)  d_in[1];
    const float* feat    = (const float*)d_in[4];
    const float* W       = (const float*)d_in[5];
    const float* attn_l  = (const float*)d_in[6];
    const float* attn_r  = (const float*)d_in[7];
    float* out = (float*)d_out;

    const int N = in_sizes[0] - 1;   // 50000

    // ws: Hb bf16 [N*256] | arow f32 [N*4] | acol f32 [N*4] | Wt bf16 [64K]
    ushortT* Hb   = (ushortT*)d_ws;
    float*   arow = (float*)(Hb + (size_t)N * HF);
    float*   acol = arow + (size_t)N * NUM_HEADS;
    ushortT* Wt   = (ushortT*)(acol + (size_t)N * NUM_HEADS);

    conv_wt<<<256, 256, 0, stream>>>(W, Wt);

    dim3 ggrid((N + 63) / 64);
    gat_gemm_fused<<<ggrid, 256, 0, stream>>>(feat, Wt, attn_l, attn_r,
                                              Hb, arow, acol, N);

    gat_aggregate3<<<(N + 3) / 4, 256, 0, stream>>>(Hb, arow, acol, col_ind, out, N);
}